// Round 1
// baseline (568.513 us; speedup 1.0000x reference)
//
#include <hip/hip_runtime.h>

// Problem constants (match reference file)
constexpr int D = 128;       // node feature dim
constexpr int R = 64;        // edge feature dim (in = out)
constexpr int CAP = 64;      // per-dst bucket capacity (in-deg ~ Poisson(16))
constexpr int OVF_CAP = 65536;

static __device__ __forceinline__ float4 f4fma(float a, float4 w, float4 c) {
  c.x = fmaf(a, w.x, c.x); c.y = fmaf(a, w.y, c.y);
  c.z = fmaf(a, w.z, c.z); c.w = fmaf(a, w.w, c.w);
  return c;
}

__global__ void k_init(int* deg_out, int* deg_in, int* cursor, int* ovf_cnt, int n) {
  int i = blockIdx.x * blockDim.x + threadIdx.x;
  if (i < n) { deg_out[i] = 1; deg_in[i] = 1; cursor[i] = 0; }  // =1: self loop
  if (i == 0) ovf_cnt[0] = 0;
}

__global__ void k_deg(const int* __restrict__ src, const int* __restrict__ dst,
                      int* deg_out, int* deg_in, int e) {
  int i = blockIdx.x * blockDim.x + threadIdx.x;
  if (i < e) {
    atomicAdd(&deg_out[src[i]], 1);
    atomicAdd(&deg_in[dst[i]], 1);
  }
}

__global__ void k_norm(const int* __restrict__ deg_out, const int* __restrict__ deg_in,
                       float* ns, float* nd, int n) {
  int i = blockIdx.x * blockDim.x + threadIdx.x;
  if (i < n) {
    ns[i] = rsqrtf((float)deg_out[i]);
    nd[i] = rsqrtf((float)deg_in[i]);
  }
}

__global__ void k_fill(const int* __restrict__ src, const int* __restrict__ dst,
                       int* cursor, int* bucket, int* ovf_cnt, int2* ovf, int e) {
  int i = blockIdx.x * blockDim.x + threadIdx.x;
  if (i >= e) return;
  int d = dst[i], s = src[i];
  int slot = atomicAdd(&cursor[d], 1);
  if (slot < CAP) bucket[(size_t)d * CAP + slot] = s;
  else {
    int oi = atomicAdd(ovf_cnt, 1);
    if (oi < OVF_CAP) ovf[oi] = make_int2(s, d);
  }
}

// One 32-lane group per node; each lane holds a float4 (D=128 = 32*4).
// agg[v] = x[v]*ns[v] (self loop) + sum_{(s->v)} x[s]*ns[s]   (norm_dst applied later)
__global__ __launch_bounds__(256) void k_agg(const float* __restrict__ X,
                                             const float* __restrict__ ns,
                                             const int* __restrict__ cursor,
                                             const int* __restrict__ bucket,
                                             float* __restrict__ agg, int n) {
  int g = threadIdx.x >> 5, lane = threadIdx.x & 31;
  int v = blockIdx.x * 8 + g;
  if (v >= n) return;
  float4 acc;
  {
    float4 xv = ((const float4*)(X + (size_t)v * D))[lane];
    float s = ns[v];
    acc.x = xv.x * s; acc.y = xv.y * s; acc.z = xv.z * s; acc.w = xv.w * s;
  }
  int cnt = min(cursor[v], CAP);
  const int* bk = bucket + (size_t)v * CAP;
  int i = 0;
  for (; i + 4 <= cnt; i += 4) {
    int s0 = bk[i], s1 = bk[i + 1], s2 = bk[i + 2], s3 = bk[i + 3];
    float n0 = ns[s0], n1 = ns[s1], n2 = ns[s2], n3 = ns[s3];
    float4 x0 = ((const float4*)(X + (size_t)s0 * D))[lane];
    float4 x1 = ((const float4*)(X + (size_t)s1 * D))[lane];
    float4 x2 = ((const float4*)(X + (size_t)s2 * D))[lane];
    float4 x3 = ((const float4*)(X + (size_t)s3 * D))[lane];
    acc = f4fma(n0, x0, acc); acc = f4fma(n1, x1, acc);
    acc = f4fma(n2, x2, acc); acc = f4fma(n3, x3, acc);
  }
  for (; i < cnt; ++i) {
    int s0 = bk[i];
    float4 x0 = ((const float4*)(X + (size_t)s0 * D))[lane];
    acc = f4fma(ns[s0], x0, acc);
  }
  ((float4*)(agg + (size_t)v * D))[lane] = acc;
}

// Rare overflow edges (slot >= CAP): f32 atomics, normally zero work.
__global__ __launch_bounds__(128) void k_ovf(const float* __restrict__ X,
                                             const float* __restrict__ ns,
                                             const int* __restrict__ ovf_cnt,
                                             const int2* __restrict__ ovf,
                                             float* agg) {
  int m = min(ovf_cnt[0], OVF_CAP);
  int t = threadIdx.x;
  for (int i = blockIdx.x; i < m; i += gridDim.x) {
    int2 e = ovf[i];
    atomicAdd(&agg[(size_t)e.y * D + t], X[(size_t)e.x * D + t] * ns[e.x]);
  }
}

// out[r] = relu( (agg[r] * nd[r]) @ W + b ) ; nd folded into epilogue.
// 256 thr: thread handles 2 rows x 4 cols; 16 rows per block-iter; W in LDS (64KB).
__global__ __launch_bounds__(256) void k_gemm_relu(const float* __restrict__ A,
                                                   const float* __restrict__ ndv,
                                                   const float* __restrict__ W,
                                                   const float* __restrict__ bias,
                                                   float* __restrict__ out, int n) {
  __shared__ float Wl[D * D];  // 64 KiB
  int t = threadIdx.x;
  for (int i = t; i < (D * D) / 4; i += 256) ((float4*)Wl)[i] = ((const float4*)W)[i];
  __syncthreads();
  int r2 = (t >> 5) * 2;       // 0,2,...,14
  int cg = (t & 31) * 4;       // col group
  float4 bb = *(const float4*)(bias + cg);
  for (int row0 = blockIdx.x * 16; row0 < n; row0 += gridDim.x * 16) {
    int ra = row0 + r2, rb = ra + 1;
    if (ra >= n) continue;     // no __syncthreads inside loop -> safe
    bool hb = (rb < n);
    const float4* A0 = (const float4*)(A + (size_t)ra * D);
    const float4* A1 = (const float4*)(A + (size_t)(hb ? rb : ra) * D);
    float4 s0 = make_float4(0.f, 0.f, 0.f, 0.f);
    float4 s1 = make_float4(0.f, 0.f, 0.f, 0.f);
#pragma unroll 8
    for (int k4 = 0; k4 < 32; ++k4) {
      float4 a0 = A0[k4];
      float4 a1 = A1[k4];
      const float* wp = Wl + (k4 << 9) + cg;
      float4 w;
      w = *(const float4*)(wp);       s0 = f4fma(a0.x, w, s0); s1 = f4fma(a1.x, w, s1);
      w = *(const float4*)(wp + 128); s0 = f4fma(a0.y, w, s0); s1 = f4fma(a1.y, w, s1);
      w = *(const float4*)(wp + 256); s0 = f4fma(a0.z, w, s0); s1 = f4fma(a1.z, w, s1);
      w = *(const float4*)(wp + 384); s0 = f4fma(a0.w, w, s0); s1 = f4fma(a1.w, w, s1);
    }
    {
      float ndr = ndv[ra];
      float4 o;
      o.x = fmaxf(fmaf(s0.x, ndr, bb.x), 0.f);
      o.y = fmaxf(fmaf(s0.y, ndr, bb.y), 0.f);
      o.z = fmaxf(fmaf(s0.z, ndr, bb.z), 0.f);
      o.w = fmaxf(fmaf(s0.w, ndr, bb.w), 0.f);
      *(float4*)(out + (size_t)ra * D + cg) = o;
    }
    if (hb) {
      float ndr = ndv[rb];
      float4 o;
      o.x = fmaxf(fmaf(s1.x, ndr, bb.x), 0.f);
      o.y = fmaxf(fmaf(s1.y, ndr, bb.y), 0.f);
      o.z = fmaxf(fmaf(s1.z, ndr, bb.z), 0.f);
      o.w = fmaxf(fmaf(s1.w, ndr, bb.w), 0.f);
      *(float4*)(out + (size_t)rb * D + cg) = o;
    }
  }
}

// e_h rows [0,E): text_h[row] @ relW + relb ; rows [E,E+N): relb (zero-filled text).
__global__ __launch_bounds__(256) void k_rel(const float* __restrict__ T,
                                             const float* __restrict__ Wr,
                                             const float* __restrict__ br,
                                             float* __restrict__ out,
                                             int e, int ntot) {
  __shared__ float Wl[R * R];  // 16 KiB
  __shared__ float bl[R];
  int t = threadIdx.x;
  for (int i = t; i < (R * R) / 4; i += 256) ((float4*)Wl)[i] = ((const float4*)Wr)[i];
  if (t < R / 4) ((float4*)bl)[t] = ((const float4*)br)[t];
  __syncthreads();
  int row = blockIdx.x * 256 + t;
  if (row >= ntot) return;
  float4 acc[16];
#pragma unroll
  for (int j = 0; j < 16; ++j) acc[j] = ((float4*)bl)[j];
  if (row < e) {
    const float4* Tr = (const float4*)(T + (size_t)row * R);
    for (int q = 0; q < 16; ++q) {        // 4 k-values per iter
      float4 a4 = Tr[q];
      const float* wrow = Wl + (q << 8);  // q*4*64
#pragma unroll
      for (int kk = 0; kk < 4; ++kk) {
        float a = (kk == 0) ? a4.x : (kk == 1) ? a4.y : (kk == 2) ? a4.z : a4.w;
        const float4* w4 = (const float4*)(wrow + (kk << 6));
#pragma unroll
        for (int j = 0; j < 16; ++j) acc[j] = f4fma(a, w4[j], acc[j]);
      }
    }
  }
  float4* op = (float4*)(out + (size_t)row * R);
#pragma unroll
  for (int j = 0; j < 16; ++j) op[j] = acc[j];
}

extern "C" void kernel_launch(void* const* d_in, const int* in_sizes, int n_in,
                              void* d_out, int out_size, void* d_ws, size_t ws_size,
                              hipStream_t stream) {
  const int*   src  = (const int*)d_in[0];
  const int*   dst  = (const int*)d_in[1];
  const float* x    = (const float*)d_in[2];
  const float* text = (const float*)d_in[3];
  const float* W1   = (const float*)d_in[4];
  const float* b1   = (const float*)d_in[5];
  const float* W2   = (const float*)d_in[6];
  const float* b2   = (const float*)d_in[7];
  const float* relW = (const float*)d_in[8];
  const float* relb = (const float*)d_in[9];

  const int E = in_sizes[0];
  const int N = in_sizes[2] / D;

  float* outH = (float*)d_out;
  float* outE = outH + (size_t)N * D;

  // workspace carve-out (256B aligned)
  char* w = (char*)d_ws;
  auto alloc = [&](size_t bytes) -> void* {
    void* p = (void*)w;
    w += (bytes + 255) & ~(size_t)255;
    return p;
  };
  int*   deg_out  = (int*)alloc((size_t)N * 4);
  int*   deg_in   = (int*)alloc((size_t)N * 4);
  int*   cursor   = (int*)alloc((size_t)N * 4);
  float* norm_src = (float*)alloc((size_t)N * 4);
  float* norm_dst = (float*)alloc((size_t)N * 4);
  int*   ovf_cnt  = (int*)alloc(256);
  int2*  ovf      = (int2*)alloc((size_t)OVF_CAP * 8);
  int*   bucket   = (int*)alloc((size_t)N * CAP * 4);
  float* agg      = (float*)alloc((size_t)N * D * 4);

  int nbN = (N + 255) / 256;
  int nbE = (E + 255) / 256;

  k_init<<<nbN, 256, 0, stream>>>(deg_out, deg_in, cursor, ovf_cnt, N);
  k_deg<<<nbE, 256, 0, stream>>>(src, dst, deg_out, deg_in, E);
  k_norm<<<nbN, 256, 0, stream>>>(deg_out, deg_in, norm_src, norm_dst, N);
  k_fill<<<nbE, 256, 0, stream>>>(src, dst, cursor, bucket, ovf_cnt, ovf, E);

  // layer 1: h1 -> outH
  k_agg<<<(N + 7) / 8, 256, 0, stream>>>(x, norm_src, cursor, bucket, agg, N);
  k_ovf<<<64, 128, 0, stream>>>(x, norm_src, ovf_cnt, ovf, agg);
  k_gemm_relu<<<1024, 256, 0, stream>>>(agg, norm_dst, W1, b1, outH, N);

  // layer 2: h2 -> outH (reads outH as input, writes same region after agg)
  k_agg<<<(N + 7) / 8, 256, 0, stream>>>(outH, norm_src, cursor, bucket, agg, N);
  k_ovf<<<64, 128, 0, stream>>>(outH, norm_src, ovf_cnt, ovf, agg);
  k_gemm_relu<<<1024, 256, 0, stream>>>(agg, norm_dst, W2, b2, outH, N);

  // edge features
  int ntot = E + N;
  k_rel<<<(ntot + 255) / 256, 256, 0, stream>>>(text, relW, relb, outE, E, ntot);
}